// Round 5
// baseline (452.153 us; speedup 1.0000x reference)
//
#include <hip/hip_runtime.h>

#define NE 500000      // edges
#define DIMK 256       // embedding dim
#define H1 128
#define H2 64
#define EPSBN 1e-5f
#define GRID1 512
#define NT1 1954                 // tiles of 256 edges
#define GRID2 768
#define NJOBS2 NT1

typedef _Float16 half8 __attribute__((ext_vector_type(8)));
typedef float f32x4 __attribute__((ext_vector_type(4)));
typedef unsigned short ushort8 __attribute__((ext_vector_type(8)));

typedef const __attribute__((address_space(1))) void* gas1_t;
typedef __attribute__((address_space(3))) void* las3_t;

static __device__ __forceinline__ half8 habs8(half8 x) {
  ushort8 u = __builtin_bit_cast(ushort8, x);
  u &= (unsigned short)0x7FFF;
  return __builtin_bit_cast(half8, u);
}
static __device__ __forceinline__ float h2f(unsigned int u) {
  return (float)__builtin_bit_cast(_Float16, (unsigned short)(u & 0xffff));
}
static __device__ __forceinline__ unsigned packf16(float a, float b) {
  unsigned lo = (unsigned)__builtin_bit_cast(unsigned short, (_Float16)a);
  unsigned hi = (unsigned)__builtin_bit_cast(unsigned short, (_Float16)b);
  return lo | (hi << 16);
}
// async global->LDS, 16B per lane; LDS dest wave-uniform base + lane*16
static __device__ __forceinline__ void gload_lds16(const _Float16* src, _Float16* dst) {
  __builtin_amdgcn_global_load_lds((gas1_t)src, (las3_t)dst, 16, 0, 0);
}

#define SB0 __builtin_amdgcn_sched_barrier(0)

// c0[j] = b1[j] + step @ W1[768:800, j]
__global__ void k_prep(const float* __restrict__ W1, const float* __restrict__ b1,
                       const float* __restrict__ step, float* __restrict__ c0) {
  const int j = threadIdx.x;
  if (j < H1) {
    float a = b1[j];
#pragma unroll
    for (int tt = 0; tt < 32; ++tt) a += step[tt] * W1[(768 + tt) * H1 + j];
    c0[j] = a;
  }
}

// fp32 emb -> fp16 copy (12.8M elems, 8/thread, exact grid)
__global__ void k_prep16(const float* __restrict__ emb, _Float16* __restrict__ embh) {
  const int i = (blockIdx.x * 256 + threadIdx.x) * 8;
  const float4 a = *(const float4*)(emb + i);
  const float4 b = *(const float4*)(emb + i + 4);
  half8 h;
  h[0] = (_Float16)a.x; h[1] = (_Float16)a.y; h[2] = (_Float16)a.z; h[3] = (_Float16)a.w;
  h[4] = (_Float16)b.x; h[5] = (_Float16)b.y; h[6] = (_Float16)b.z; h[7] = (_Float16)b.w;
  *(half8*)(embh + i) = h;
}

// Build fragment-ordered B for layer1: bfrag[(s*64+kc*8+c)*64*8 + lane*8 + j]
//   = W1[s*256 + kc*32 + (lane>>4)*8 + j][c*16 + (lane&15)]   (fp16)
__global__ void k_prepB(const float* __restrict__ W1, _Float16* __restrict__ bfrag) {
  const int g = blockIdx.x * 256 + threadIdx.x;
  const int lane = g & 63, f = g >> 6;
  const int c = f & 7, kc = (f >> 3) & 7, s = f >> 6;
  const int row0 = s * 256 + kc * 32 + (lane >> 4) * 8;
  const int col = c * 16 + (lane & 15);
  half8 h;
#pragma unroll
  for (int j = 0; j < 8; ++j) h[j] = (_Float16)W1[(row0 + j) * H1 + col];
  *(half8*)(bfrag + (size_t)g * 8) = h;
}

// Stage one kc-slice of B (24KB = 1536 half8) into LDS buffer q.
// 256 threads x 6 issues: sc = jj*4+w in [0,24), lane offset auto.
#define STAGE1(q, kcv) do {                                                   \
    _Pragma("unroll")                                                         \
    for (int jj = 0; jj < 6; ++jj) {                                          \
      const int sc = jj * 4 + w;                                              \
      const int ff = (sc >> 3) * 64 + (kcv) * 8 + (sc & 7);                   \
      gload_lds16(bfrag + ((size_t)ff * 64 + lane) * 8,                       \
                  s_B + (size_t)(q) * 12288 + sc * 512);                      \
    }                                                                         \
  } while (0)

// Layer 1 via MFMA fp16, FULL 128-col output per 256-edge tile.
// B-slices broadcast through LDS (double-buffered global_load_lds).
// A-gathers for kc+1 reload the SAME u/v registers right after the kc MFMA
// block (operands dead there) -> next-kc gather latency overlaps the closing
// barrier + stage-issue + entry barrier instead of stalling post-barrier.
__global__ __launch_bounds__(256, 2)
void k_layer1(const _Float16* __restrict__ embh, const void* __restrict__ eidx_raw,
              const float* __restrict__ grad, const float* __restrict__ W1,
              const float* __restrict__ c0, const _Float16* __restrict__ bfrag,
              _Float16* __restrict__ x1, float* __restrict__ p1) {
  __shared__ int s_src[256], s_dst[256];
  __shared__ float s_g[256];
  __shared__ float s_wg[128], s_c0[128], s_sum[128], s_sq[128];
  __shared__ __align__(16) _Float16 s_B[2 * 12288];   // 2 x 24KB B slices

  const int t = threadIdx.x, bid = blockIdx.x;
  const int w = t >> 6, lane = t & 63, quad = lane >> 4, m15 = lane & 15;

  if (t < 128) {
    s_wg[t] = W1[800 * H1 + t];
    s_c0[t] = c0[t];
    s_sum[t] = 0.f; s_sq[t] = 0.f;
  }

  const unsigned* ew = (const unsigned*)eidx_raw;
  const bool is64 = ((ew[1] | ew[3] | ew[5] | ew[7]) == 0u);
  const int* e32 = (const int*)eidx_raw;
  const long long* e64 = (const long long*)eidx_raw;

  float st_s[8] = {0, 0, 0, 0, 0, 0, 0, 0}, st_q[8] = {0, 0, 0, 0, 0, 0, 0, 0};

  for (int tile = bid; tile < NT1; tile += GRID1) {
    const int base = tile * 256;
    __syncthreads();
    {
      int e = base + t; if (e >= NE) e = NE - 1;
      if (is64) { s_src[t] = (int)e64[e]; s_dst[t] = (int)e64[NE + e]; }
      else      { s_src[t] = e32[e];      s_dst[t] = e32[NE + e]; }
      s_g[t] = grad[e];
    }
    STAGE1(0, 0);            // prologue stage of kc=0 into buf 0
    __syncthreads();         // drains stage + makes s_src visible

    const int r0 = w * 64 + m15;
    const _Float16* pu[4];
    const _Float16* pv[4];
#pragma unroll
    for (int r = 0; r < 4; ++r) {
      pu[r] = embh + (size_t)s_src[r0 + r * 16] * DIMK + quad * 8;
      pv[r] = embh + (size_t)s_dst[r0 + r * 16] * DIMK + quad * 8;
    }
    half8 u[4], v[4];
#pragma unroll
    for (int r = 0; r < 4; ++r) {         // A(kc=0): 8 loads in flight
      u[r] = *(const half8*)pu[r];
      v[r] = *(const half8*)pv[r];
    }
    f32x4 acc[4][8];
#pragma unroll
    for (int r = 0; r < 4; ++r)
#pragma unroll
      for (int c = 0; c < 8; ++c) acc[r][c] = (f32x4)0.f;

#pragma unroll 1
    for (int kc = 0; kc < 8; ++kc) {
      if (kc < 7) {
        STAGE1((kc + 1) & 1, kc + 1);     // issue next B slice (6 loads)
        // outstanding: B(kc)6 + A(kc)8 + B(kc+1)6 = 20 -> drain B(kc)
        asm volatile("s_waitcnt vmcnt(14)" ::: "memory");
      } else {
        // outstanding: B(7)6 + A(7)8 = 14 -> drain B(7)
        asm volatile("s_waitcnt vmcnt(8)" ::: "memory");
      }
      __builtin_amdgcn_s_barrier();       // all waves' stages visible
      SB0;

      half8 d[4];
#pragma unroll
      for (int r = 0; r < 4; ++r) d[r] = habs8(u[r] - v[r]);

      const half8* bq = (const half8*)s_B + (size_t)(kc & 1) * 1536 + lane;
#pragma unroll
      for (int c = 0; c < 8; ++c) {
        const half8 bu = bq[c * 64];
        const half8 bv = bq[512 + c * 64];
        const half8 bd = bq[1024 + c * 64];
#pragma unroll
        for (int r = 0; r < 4; ++r)
          acc[r][c] = __builtin_amdgcn_mfma_f32_16x16x32_f16(u[r], bu, acc[r][c], 0, 0, 0);
#pragma unroll
        for (int r = 0; r < 4; ++r)
          acc[r][c] = __builtin_amdgcn_mfma_f32_16x16x32_f16(v[r], bv, acc[r][c], 0, 0, 0);
#pragma unroll
        for (int r = 0; r < 4; ++r)
          acc[r][c] = __builtin_amdgcn_mfma_f32_16x16x32_f16(d[r], bd, acc[r][c], 0, 0, 0);
      }
      SB0;
      if (kc < 7) {                       // reload same regs for kc+1 (dead here)
#pragma unroll
        for (int r = 0; r < 4; ++r) {
          u[r] = *(const half8*)(pu[r] + (kc + 1) * 32);
          v[r] = *(const half8*)(pv[r] + (kc + 1) * 32);
        }
      }
      SB0;
      __builtin_amdgcn_s_barrier();       // done reading s_B before overwrite
    }
    // epilogue: relu + stats + packed dword stores (r2-validated mapping)
#pragma unroll
    for (int r = 0; r < 4; ++r) {
      const int erow = w * 64 + r * 16 + quad * 4;
      const int e0 = base + erow;
#pragma unroll
      for (int c = 0; c < 8; ++c) {
        const int colL = c * 16 + m15;
        const float wgv = s_wg[colL], c0v = s_c0[colL];
        float xv[4];
#pragma unroll
        for (int reg = 0; reg < 4; ++reg) {
          float x = acc[r][c][reg] + s_g[erow + reg] * wgv + c0v;
          x = fmaxf(x, 0.f);
          if (e0 + reg >= NE) x = 0.f;
          xv[reg] = x;
          st_s[c] += x; st_q[c] += x * x;
        }
        unsigned b01 = packf16(xv[0], xv[1]);
        unsigned b23 = packf16(xv[2], xv[3]);
        unsigned q01 = (unsigned)__shfl_xor((int)b01, 1);
        unsigned q23 = (unsigned)__shfl_xor((int)b23, 1);
        const int ce = colL & ~1;
        if (!(m15 & 1)) {
          if (e0 < NE)     *(unsigned*)(x1 + (size_t)e0 * H1 + ce)       = (b01 & 0xffffu) | (q01 << 16);
          if (e0 + 1 < NE) *(unsigned*)(x1 + (size_t)(e0 + 1) * H1 + ce) = (b01 >> 16) | (q01 & 0xffff0000u);
        } else {
          if (e0 + 2 < NE) *(unsigned*)(x1 + (size_t)(e0 + 2) * H1 + ce) = (q23 & 0xffffu) | (b23 << 16);
          if (e0 + 3 < NE) *(unsigned*)(x1 + (size_t)(e0 + 3) * H1 + ce) = (q23 >> 16) | (b23 & 0xffff0000u);
        }
      }
    }
  }
  __syncthreads();
#pragma unroll
  for (int c = 0; c < 8; ++c) {
    float a = st_s[c]; a += __shfl_xor(a, 16); a += __shfl_xor(a, 32);
    float b = st_q[c]; b += __shfl_xor(b, 16); b += __shfl_xor(b, 32);
    if (lane < 16) { atomicAdd(&s_sum[c * 16 + m15], a); atomicAdd(&s_sq[c * 16 + m15], b); }
  }
  __syncthreads();
  if (t < 128) {
    p1[t * GRID1 + bid] = s_sum[t];
    p1[128 * GRID1 + t * GRID1 + bid] = s_sq[t];
  }
}

// Finalize BN1 stats, fold into W2/b2 (fp32 row-major out)
__global__ void k_fin1(const float* __restrict__ p1, const float* __restrict__ g1,
                       const float* __restrict__ be1, const float* __restrict__ W2,
                       const float* __restrict__ b2, float* __restrict__ w2f,
                       float* __restrict__ b2f) {
  __shared__ float s1[128], t1[128];
  const int t = threadIdx.x;
  if (t < 128) {
    float s = 0.f, q = 0.f;
    const float4* rs = (const float4*)(p1 + t * GRID1);
    const float4* rq = (const float4*)(p1 + 128 * GRID1 + t * GRID1);
#pragma unroll 4
    for (int i = 0; i < GRID1 / 4; ++i) {
      float4 a = rs[i]; s += a.x + a.y + a.z + a.w;
      float4 b = rq[i]; q += b.x + b.y + b.z + b.w;
    }
    const float inv = 1.0f / (float)NE;
    float mean = s * inv;
    float var = q * inv - mean * mean;
    float sc = g1[t] * rsqrtf(var + EPSBN);
    s1[t] = sc; t1[t] = be1[t] - mean * sc;
  }
  __syncthreads();
  for (int i = t; i < H1 * H2; i += 256) w2f[i] = s1[i >> 6] * W2[i];
  if (t < 64) {
    float b = b2[t];
    for (int j = 0; j < 128; ++j) b += t1[j] * W2[j * 64 + t];
    b2f[t] = b;
  }
}

// Layer 2 via MFMA: x2 = relu(x1 @ W2F + b2F), B (16KB) in LDS.
// Occupancy 3 blocks/CU (acc 64 + ~80 arch fits the 170-reg budget).
__global__ __launch_bounds__(256, 3)
void k_layer2(const _Float16* __restrict__ x1, const float* __restrict__ w2f,
              const float* __restrict__ b2f, _Float16* __restrict__ x2,
              float* __restrict__ p2) {
  __shared__ __align__(16) _Float16 b_lds[8192];  // 4 ksteps x 4 coltiles frag order
  __shared__ float s_b[64], s_sum[64], s_sq[64];
  const int t = threadIdx.x, bid = blockIdx.x;
  const int w = t >> 6, lane = t & 63, quad = lane >> 4, m15 = lane & 15;

  for (int i = t; i < 8192; i += 256) {
    const int j = i & 7, li = (i >> 3) & 63, f = i >> 9;
    const int c = f & 3, kk = f >> 2;
    const int row = kk * 32 + (li >> 4) * 8 + j;
    const int col = c * 16 + (li & 15);
    b_lds[i] = (_Float16)w2f[row * H2 + col];
  }
  if (t < 64) { s_b[t] = b2f[t]; s_sum[t] = 0.f; s_sq[t] = 0.f; }
  __syncthreads();

  float st_s[4] = {0, 0, 0, 0}, st_q[4] = {0, 0, 0, 0};
  const half8* bp = (const half8*)b_lds;

  for (int job = bid; job < NJOBS2; job += GRID2) {
    const int base = job * 256;
    const _Float16* pa[4];
#pragma unroll
    for (int r = 0; r < 4; ++r) {
      int e = base + w * 64 + r * 16 + m15; if (e >= NE) e = NE - 1;
      pa[r] = x1 + (size_t)e * H1 + quad * 8;
    }
    f32x4 acc[4][4];
#pragma unroll
    for (int r = 0; r < 4; ++r)
#pragma unroll
      for (int c = 0; c < 4; ++c) acc[r][c] = (f32x4)0.f;

#pragma unroll
    for (int kk = 0; kk < 4; ++kk) {
      half8 a[4];
#pragma unroll
      for (int r = 0; r < 4; ++r) a[r] = *(const half8*)(pa[r] + kk * 32);
#pragma unroll
      for (int c = 0; c < 4; ++c) {
        const half8 bf = bp[(kk * 4 + c) * 64 + lane];
#pragma unroll
        for (int r = 0; r < 4; ++r)
          acc[r][c] = __builtin_amdgcn_mfma_f32_16x16x32_f16(a[r], bf, acc[r][c], 0, 0, 0);
      }
    }
#pragma unroll
    for (int r = 0; r < 4; ++r) {
      const int erow = w * 64 + r * 16 + quad * 4;
#pragma unroll
      for (int c = 0; c < 4; ++c) {
        const int colL = c * 16 + m15;
        const float bv = s_b[colL];
#pragma unroll
        for (int reg = 0; reg < 4; ++reg) {
          const int e = base + erow + reg;
          float x = acc[r][c][reg] + bv;
          x = fmaxf(x, 0.f);
          if (e >= NE) x = 0.f;
          st_s[c] += x; st_q[c] += x * x;
          if (e < NE) x2[(size_t)e * H2 + colL] = (_Float16)x;
        }
      }
    }
  }
  __syncthreads();
#pragma unroll
  for (int c = 0; c < 4; ++c) {
    float a = st_s[c]; a += __shfl_xor(a, 16); a += __shfl_xor(a, 32);
    float b = st_q[c]; b += __shfl_xor(b, 16); b += __shfl_xor(b, 32);
    if (lane < 16) { atomicAdd(&s_sum[c * 16 + m15], a); atomicAdd(&s_sq[c * 16 + m15], b); }
  }
  __syncthreads();
  if (t < 64) {
    p2[t * GRID2 + bid] = s_sum[t];
    p2[64 * GRID2 + t * GRID2 + bid] = s_sq[t];
  }
}

// Finalize BN2, fold into W3/b3
__global__ void k_fin2(const float* __restrict__ p2, const float* __restrict__ g2,
                       const float* __restrict__ be2, const float* __restrict__ W3,
                       const float* __restrict__ b3, float* __restrict__ w3f,
                       float* __restrict__ b3f) {
  __shared__ float tp[64];
  const int t = threadIdx.x;
  if (t < 64) {
    float s = 0.f, q = 0.f;
    const float4* rs = (const float4*)(p2 + t * GRID2);
    const float4* rq = (const float4*)(p2 + 64 * GRID2 + t * GRID2);
#pragma unroll 4
    for (int i = 0; i < GRID2 / 4; ++i) {
      float4 a = rs[i]; s += a.x + a.y + a.z + a.w;
      float4 b = rq[i]; q += b.x + b.y + b.z + b.w;
    }
    const float inv = 1.0f / (float)NE;
    float mean = s * inv;
    float var = q * inv - mean * mean;
    float sc = g2[t] * rsqrtf(var + EPSBN);
    float tt = be2[t] - mean * sc;
    w3f[t] = sc * W3[t];
    tp[t] = tt * W3[t];
  }
  __syncthreads();
  if (t == 0) {
    float b = b3[0];
    for (int j = 0; j < 64; ++j) b += tp[j];
    b3f[0] = b;
  }
}

// out = tanh(x2 @ w3f + b3f); 4 lanes per edge
__global__ __launch_bounds__(256)
void k_out(const unsigned short* __restrict__ x2, const float* __restrict__ w3f,
           const float* __restrict__ b3f, float* __restrict__ out) {
  __shared__ float s_w[64];
  __shared__ float s_b;
  const int t = threadIdx.x;
  if (t < 64) s_w[t] = w3f[t];
  if (t == 0) s_b = b3f[0];
  __syncthreads();
  const int gid = blockIdx.x * 256 + t;
  const int e = gid >> 2, p = gid & 3;
  if (e < NE) {
    const uint4* r = (const uint4*)(x2 + (size_t)e * H2 + p * 16);
    float s = 0.f;
#pragma unroll
    for (int i = 0; i < 2; ++i) {
      const uint4 u = r[i];
      const int jb = p * 16 + i * 8;
      s += h2f(u.x) * s_w[jb + 0] + h2f(u.x >> 16) * s_w[jb + 1];
      s += h2f(u.y) * s_w[jb + 2] + h2f(u.y >> 16) * s_w[jb + 3];
      s += h2f(u.z) * s_w[jb + 4] + h2f(u.z >> 16) * s_w[jb + 5];
      s += h2f(u.w) * s_w[jb + 6] + h2f(u.w >> 16) * s_w[jb + 7];
    }
    s += __shfl_xor(s, 1);
    s += __shfl_xor(s, 2);
    if (p == 0) out[e] = tanhf(s + s_b);
  }
}

extern "C" void kernel_launch(void* const* d_in, const int* in_sizes, int n_in,
                              void* d_out, int out_size, void* d_ws, size_t ws_size,
                              hipStream_t stream) {
  const float* emb  = (const float*)d_in[0];
  const float* grad = (const float*)d_in[1];
  const float* step = (const float*)d_in[2];
  const float* W1   = (const float*)d_in[3];
  const float* b1   = (const float*)d_in[4];
  const float* g1   = (const float*)d_in[5];
  const float* be1  = (const float*)d_in[6];
  const float* W2   = (const float*)d_in[7];
  const float* b2   = (const float*)d_in[8];
  const float* g2   = (const float*)d_in[9];
  const float* be2  = (const float*)d_in[10];
  const float* W3   = (const float*)d_in[11];
  const float* b3   = (const float*)d_in[12];
  const void*  eidx = (const void*)d_in[13];
  float* out = (float*)d_out;

  char* ws = (char*)d_ws;
  // region A (64MB): embh (25.6MB) + bfrag + c0 + p1 during layer1/fin1;
  // x2 overwrites the whole region in layer2.
  _Float16* embh  = (_Float16*)(ws + 0);
  _Float16* x2    = (_Float16*)(ws + 0);
  _Float16* bfrag = (_Float16*)(ws + 25600000LL);  // 196,608 B
  float*    c0    = (float*)(ws + 25796608LL);     // 512 B
  float*    p1    = (float*)(ws + 26000000LL);     // 524,288 B (dead before layer2)
  _Float16* x1    = (_Float16*)(ws + 64000000LL);  // 128,000,000 B
  float* p2  = (float*)(ws + 192000000LL);         // 393,216 B (64 sums + 64 sqs x 768)
  float* w2f = (float*)(ws + 192524288LL);         // 32,768 B
  float* b2f = (float*)(ws + 192557056LL);         // 256 B
  float* w3f = (float*)(ws + 192557312LL);         // 256 B
  float* b3f = (float*)(ws + 192557568LL);         // 16 B

  k_prep  <<<1,    256, 0, stream>>>(W1, b1, step, c0);
  k_prep16<<<6250, 256, 0, stream>>>(emb, embh);
  k_prepB <<<48,   256, 0, stream>>>(W1, bfrag);
  k_layer1<<<GRID1,256, 0, stream>>>(embh, eidx, grad, W1, c0, bfrag, x1, p1);
  k_fin1  <<<1,    256, 0, stream>>>(p1, g1, be1, W2, b2, w2f, b2f);
  k_layer2<<<GRID2,256, 0, stream>>>(x1, w2f, b2f, x2, p2);
  k_fin2  <<<1,    128, 0, stream>>>(p2, g2, be2, W3, b3, w3f, b3f);
  k_out   <<<7813, 256, 0, stream>>>((const unsigned short*)x2, w3f, b3f, out);
}

// Round 6
// 338.754 us; speedup vs baseline: 1.3348x; 1.3348x over previous
//
#include <hip/hip_runtime.h>

#define NE 500000      // edges
#define DIMK 256       // embedding dim
#define H1 128
#define H2 64
#define EPSBN 1e-5f
#define GRID1 512
#define NT1 1954                 // tiles of 256 edges
#define GRID2 512
#define NJOBS2 NT1

typedef _Float16 half8 __attribute__((ext_vector_type(8)));
typedef float f32x4 __attribute__((ext_vector_type(4)));
typedef unsigned short ushort8 __attribute__((ext_vector_type(8)));

typedef const __attribute__((address_space(1))) void* gas1_t;
typedef __attribute__((address_space(3))) void* las3_t;

static __device__ __forceinline__ half8 habs8(half8 x) {
  ushort8 u = __builtin_bit_cast(ushort8, x);
  u &= (unsigned short)0x7FFF;
  return __builtin_bit_cast(half8, u);
}
static __device__ __forceinline__ float h2f(unsigned int u) {
  return (float)__builtin_bit_cast(_Float16, (unsigned short)(u & 0xffff));
}
static __device__ __forceinline__ unsigned packf16(float a, float b) {
  unsigned lo = (unsigned)__builtin_bit_cast(unsigned short, (_Float16)a);
  unsigned hi = (unsigned)__builtin_bit_cast(unsigned short, (_Float16)b);
  return lo | (hi << 16);
}
// async global->LDS, 16B per lane; LDS dest wave-uniform base + lane*16
static __device__ __forceinline__ void gload_lds16(const _Float16* src, _Float16* dst) {
  __builtin_amdgcn_global_load_lds((gas1_t)src, (las3_t)dst, 16, 0, 0);
}

// Fused prep: blocks 0..6249 = fp32 emb -> fp16 copy; blocks 6250..6297 =
// fragment-ordered B build; block 6298 = c0 = b1 + step @ W1[768:800,:]
__global__ void k_preall(const float* __restrict__ emb, _Float16* __restrict__ embh,
                         const float* __restrict__ W1, _Float16* __restrict__ bfrag,
                         const float* __restrict__ b1, const float* __restrict__ step,
                         float* __restrict__ c0) {
  const int bid = blockIdx.x, t = threadIdx.x;
  if (bid < 6250) {
    const int i = (bid * 256 + t) * 8;
    const float4 a = *(const float4*)(emb + i);
    const float4 b = *(const float4*)(emb + i + 4);
    half8 h;
    h[0] = (_Float16)a.x; h[1] = (_Float16)a.y; h[2] = (_Float16)a.z; h[3] = (_Float16)a.w;
    h[4] = (_Float16)b.x; h[5] = (_Float16)b.y; h[6] = (_Float16)b.z; h[7] = (_Float16)b.w;
    *(half8*)(embh + i) = h;
  } else if (bid < 6298) {
    // bfrag[(s*64+kc*8+c)*64*8 + lane*8 + j] = W1[s*256+kc*32+(lane>>4)*8+j][c*16+(lane&15)]
    const int g = (bid - 6250) * 256 + t;
    const int lane = g & 63, f = g >> 6;
    const int c = f & 7, kc = (f >> 3) & 7, s = f >> 6;
    const int row0 = s * 256 + kc * 32 + (lane >> 4) * 8;
    const int col = c * 16 + (lane & 15);
    half8 h;
#pragma unroll
    for (int j = 0; j < 8; ++j) h[j] = (_Float16)W1[(row0 + j) * H1 + col];
    *(half8*)(bfrag + (size_t)g * 8) = h;
  } else {
    if (t < H1) {
      float a = b1[t];
#pragma unroll
      for (int tt = 0; tt < 32; ++tt) a += step[tt] * W1[(768 + tt) * H1 + t];
      c0[t] = a;
    }
  }
}

// Stage one kc-slice of B (24KB = 1536 half8) into LDS buffer q.
// 256 threads x 6 issues: sc = jj*4+w in [0,24), lane offset auto.
#define STAGE1(q, kcv) do {                                                   \
    _Pragma("unroll")                                                         \
    for (int jj = 0; jj < 6; ++jj) {                                          \
      const int sc = jj * 4 + w;                                              \
      const int ff = (sc >> 3) * 64 + (kcv) * 8 + (sc & 7);                   \
      gload_lds16(bfrag + ((size_t)ff * 64 + lane) * 8,                       \
                  s_B + (size_t)(q) * 12288 + sc * 512);                      \
    }                                                                         \
  } while (0)

// Layer 1 via MFMA fp16 (round-1 known-good, 153us): FULL 128-col output per
// 256-edge tile; B-slices broadcast through LDS (double-buffered
// global_load_lds, counted vmcnt(6)); A-gathers loaded after entry barrier.
// NOTE: acc[4][8]=128 AGPR + 128 VGPR is exactly the 256 budget — any added
// live state (prefetch regs, NT stores, packed-store temps) spills (r2/r3/r5).
__global__ __launch_bounds__(256, 2)
void k_layer1(const _Float16* __restrict__ embh, const void* __restrict__ eidx_raw,
              const float* __restrict__ grad, const float* __restrict__ W1,
              const float* __restrict__ c0, const _Float16* __restrict__ bfrag,
              _Float16* __restrict__ x1, float* __restrict__ p1) {
  __shared__ int s_src[256], s_dst[256];
  __shared__ float s_g[256];
  __shared__ float s_wg[128], s_c0[128], s_sum[128], s_sq[128];
  __shared__ __align__(16) _Float16 s_B[2 * 12288];   // 2 x 24KB B slices

  const int t = threadIdx.x, bid = blockIdx.x;
  const int w = t >> 6, lane = t & 63, quad = lane >> 4, m15 = lane & 15;

  if (t < 128) {
    s_wg[t] = W1[800 * H1 + t];
    s_c0[t] = c0[t];
    s_sum[t] = 0.f; s_sq[t] = 0.f;
  }

  const unsigned* ew = (const unsigned*)eidx_raw;
  const bool is64 = ((ew[1] | ew[3] | ew[5] | ew[7]) == 0u);
  const int* e32 = (const int*)eidx_raw;
  const long long* e64 = (const long long*)eidx_raw;

  float st_s[8] = {0, 0, 0, 0, 0, 0, 0, 0}, st_q[8] = {0, 0, 0, 0, 0, 0, 0, 0};

  for (int tile = bid; tile < NT1; tile += GRID1) {
    const int base = tile * 256;
    __syncthreads();
    {
      int e = base + t; if (e >= NE) e = NE - 1;
      if (is64) { s_src[t] = (int)e64[e]; s_dst[t] = (int)e64[NE + e]; }
      else      { s_src[t] = e32[e];      s_dst[t] = e32[NE + e]; }
      s_g[t] = grad[e];
    }
    STAGE1(0, 0);            // prologue stage of kc=0 into buf 0
    __syncthreads();

    const int r0 = w * 64 + m15;
    const _Float16* pu[4];
    const _Float16* pv[4];
#pragma unroll
    for (int r = 0; r < 4; ++r) {
      pu[r] = embh + (size_t)s_src[r0 + r * 16] * DIMK + quad * 8;
      pv[r] = embh + (size_t)s_dst[r0 + r * 16] * DIMK + quad * 8;
    }
    f32x4 acc[4][8];
#pragma unroll
    for (int r = 0; r < 4; ++r)
#pragma unroll
      for (int c = 0; c < 8; ++c) acc[r][c] = (f32x4)0.f;

#pragma unroll 1
    for (int kc = 0; kc < 8; ++kc) {
      if (kc < 7) {
        STAGE1((kc + 1) & 1, kc + 1);                 // issue next slice, don't wait
        asm volatile("s_waitcnt vmcnt(6)" ::: "memory");  // current slice done
      } else {
        asm volatile("s_waitcnt vmcnt(0)" ::: "memory");
      }
      __builtin_amdgcn_s_barrier();                   // all waves' stages visible
      __builtin_amdgcn_sched_barrier(0);

      half8 u[4], v[4], d[4];
#pragma unroll
      for (int r = 0; r < 4; ++r) {
        u[r] = *(const half8*)(pu[r] + kc * 32);
        v[r] = *(const half8*)(pv[r] + kc * 32);
      }
#pragma unroll
      for (int r = 0; r < 4; ++r) d[r] = habs8(u[r] - v[r]);

      const half8* bq = (const half8*)s_B + (size_t)(kc & 1) * 1536 + lane;
#pragma unroll
      for (int c = 0; c < 8; ++c) {
        const half8 bu = bq[c * 64];
        const half8 bv = bq[512 + c * 64];
        const half8 bd = bq[1024 + c * 64];
#pragma unroll
        for (int r = 0; r < 4; ++r)
          acc[r][c] = __builtin_amdgcn_mfma_f32_16x16x32_f16(u[r], bu, acc[r][c], 0, 0, 0);
#pragma unroll
        for (int r = 0; r < 4; ++r)
          acc[r][c] = __builtin_amdgcn_mfma_f32_16x16x32_f16(v[r], bv, acc[r][c], 0, 0, 0);
#pragma unroll
        for (int r = 0; r < 4; ++r)
          acc[r][c] = __builtin_amdgcn_mfma_f32_16x16x32_f16(d[r], bd, acc[r][c], 0, 0, 0);
      }
      __builtin_amdgcn_sched_barrier(0);
      __builtin_amdgcn_s_barrier();                   // done reading before overwrite
    }
    // epilogue: D layout col=lane&15, row=quad*4+reg (scalar stores — r1-exact)
#pragma unroll
    for (int r = 0; r < 4; ++r) {
      const int erow = w * 64 + r * 16 + quad * 4;
#pragma unroll
      for (int c = 0; c < 8; ++c) {
        const int colL = c * 16 + m15;
        const float wgv = s_wg[colL], c0v = s_c0[colL];
#pragma unroll
        for (int reg = 0; reg < 4; ++reg) {
          const int e = base + erow + reg;
          float x = acc[r][c][reg] + s_g[erow + reg] * wgv + c0v;
          x = fmaxf(x, 0.f);
          if (e >= NE) x = 0.f;
          st_s[c] += x; st_q[c] += x * x;
          if (e < NE) x1[(size_t)e * H1 + colL] = (_Float16)x;
        }
      }
    }
  }
  __syncthreads();
#pragma unroll
  for (int c = 0; c < 8; ++c) {
    float a = st_s[c]; a += __shfl_xor(a, 16); a += __shfl_xor(a, 32);
    float b = st_q[c]; b += __shfl_xor(b, 16); b += __shfl_xor(b, 32);
    if (lane < 16) { atomicAdd(&s_sum[c * 16 + m15], a); atomicAdd(&s_sq[c * 16 + m15], b); }
  }
  __syncthreads();
  if (t < 128) {
    p1[t * GRID1 + bid] = s_sum[t];
    p1[128 * GRID1 + t * GRID1 + bid] = s_sq[t];
  }
}

// Finalize BN1 stats, fold into W2/b2 (fp32 row-major out)
__global__ void k_fin1(const float* __restrict__ p1, const float* __restrict__ g1,
                       const float* __restrict__ be1, const float* __restrict__ W2,
                       const float* __restrict__ b2, float* __restrict__ w2f,
                       float* __restrict__ b2f) {
  __shared__ float s1[128], t1[128];
  const int t = threadIdx.x;
  if (t < 128) {
    float s = 0.f, q = 0.f;
    const float4* rs = (const float4*)(p1 + t * GRID1);
    const float4* rq = (const float4*)(p1 + 128 * GRID1 + t * GRID1);
#pragma unroll 4
    for (int i = 0; i < GRID1 / 4; ++i) {
      float4 a = rs[i]; s += a.x + a.y + a.z + a.w;
      float4 b = rq[i]; q += b.x + b.y + b.z + b.w;
    }
    const float inv = 1.0f / (float)NE;
    float mean = s * inv;
    float var = q * inv - mean * mean;
    float sc = g1[t] * rsqrtf(var + EPSBN);
    s1[t] = sc; t1[t] = be1[t] - mean * sc;
  }
  __syncthreads();
  for (int i = t; i < H1 * H2; i += 256) w2f[i] = s1[i >> 6] * W2[i];
  if (t < 64) {
    float b = b2[t];
    for (int j = 0; j < 128; ++j) b += t1[j] * W2[j * 64 + t];
    b2f[t] = b;
  }
}

// Layer 2 via MFMA (round-0 structure, LB(256,2)): x2 = relu(x1 @ W2F + b2F),
// B (16KB) resident in LDS. Epilogue upgraded to packed dword stores
// (32 dword stores replace 64 ushort stores; register-light here: acc=64).
__global__ __launch_bounds__(256, 2)
void k_layer2(const _Float16* __restrict__ x1, const float* __restrict__ w2f,
              const float* __restrict__ b2f, _Float16* __restrict__ x2,
              float* __restrict__ p2) {
  __shared__ __align__(16) _Float16 b_lds[8192];  // 4 ksteps x 4 coltiles frag order
  __shared__ float s_b[64], s_sum[64], s_sq[64];
  const int t = threadIdx.x, bid = blockIdx.x;
  const int w = t >> 6, lane = t & 63, quad = lane >> 4, m15 = lane & 15;

  for (int i = t; i < 8192; i += 256) {
    const int j = i & 7, li = (i >> 3) & 63, f = i >> 9;
    const int c = f & 3, kk = f >> 2;
    const int row = kk * 32 + (li >> 4) * 8 + j;
    const int col = c * 16 + (li & 15);
    b_lds[i] = (_Float16)w2f[row * H2 + col];
  }
  if (t < 64) { s_b[t] = b2f[t]; s_sum[t] = 0.f; s_sq[t] = 0.f; }
  __syncthreads();

  float st_s[4] = {0, 0, 0, 0}, st_q[4] = {0, 0, 0, 0};
  const half8* bp = (const half8*)b_lds;

  for (int job = bid; job < NJOBS2; job += GRID2) {
    const int base = job * 256;
    const _Float16* pa[4];
#pragma unroll
    for (int r = 0; r < 4; ++r) {
      int e = base + w * 64 + r * 16 + m15; if (e >= NE) e = NE - 1;
      pa[r] = x1 + (size_t)e * H1 + quad * 8;
    }
    f32x4 acc[4][4];
#pragma unroll
    for (int r = 0; r < 4; ++r)
#pragma unroll
      for (int c = 0; c < 4; ++c) acc[r][c] = (f32x4)0.f;

#pragma unroll
    for (int kk = 0; kk < 4; ++kk) {
      half8 a[4];
#pragma unroll
      for (int r = 0; r < 4; ++r) a[r] = *(const half8*)(pa[r] + kk * 32);
#pragma unroll
      for (int c = 0; c < 4; ++c) {
        const half8 bf = bp[(kk * 4 + c) * 64 + lane];
#pragma unroll
        for (int r = 0; r < 4; ++r)
          acc[r][c] = __builtin_amdgcn_mfma_f32_16x16x32_f16(a[r], bf, acc[r][c], 0, 0, 0);
      }
    }
#pragma unroll
    for (int r = 0; r < 4; ++r) {
      const int e0 = base + w * 64 + r * 16 + quad * 4;
#pragma unroll
      for (int c = 0; c < 4; ++c) {
        const int colL = c * 16 + m15;
        const float bv = s_b[colL];
        float xv[4];
#pragma unroll
        for (int reg = 0; reg < 4; ++reg) {
          float x = acc[r][c][reg] + bv;
          x = fmaxf(x, 0.f);
          if (e0 + reg >= NE) x = 0.f;
          xv[reg] = x;
          st_s[c] += x; st_q[c] += x * x;
        }
        unsigned b01 = packf16(xv[0], xv[1]);
        unsigned b23 = packf16(xv[2], xv[3]);
        unsigned q01 = (unsigned)__shfl_xor((int)b01, 1);
        unsigned q23 = (unsigned)__shfl_xor((int)b23, 1);
        const int ce = colL & ~1;
        if (!(m15 & 1)) {
          if (e0 < NE)     *(unsigned*)(x2 + (size_t)e0 * H2 + ce)       = (b01 & 0xffffu) | (q01 << 16);
          if (e0 + 1 < NE) *(unsigned*)(x2 + (size_t)(e0 + 1) * H2 + ce) = (b01 >> 16) | (q01 & 0xffff0000u);
        } else {
          if (e0 + 2 < NE) *(unsigned*)(x2 + (size_t)(e0 + 2) * H2 + ce) = (q23 & 0xffffu) | (b23 << 16);
          if (e0 + 3 < NE) *(unsigned*)(x2 + (size_t)(e0 + 3) * H2 + ce) = (q23 >> 16) | (b23 & 0xffff0000u);
        }
      }
    }
  }
  __syncthreads();
#pragma unroll
  for (int c = 0; c < 4; ++c) {
    float a = st_s[c]; a += __shfl_xor(a, 16); a += __shfl_xor(a, 32);
    float b = st_q[c]; b += __shfl_xor(b, 16); b += __shfl_xor(b, 32);
    if (lane < 16) { atomicAdd(&s_sum[c * 16 + m15], a); atomicAdd(&s_sq[c * 16 + m15], b); }
  }
  __syncthreads();
  if (t < 64) {
    p2[t * 512 + bid] = s_sum[t];
    p2[64 * 512 + t * 512 + bid] = s_sq[t];
  }
}

// Finalize BN2, fold into W3/b3
__global__ void k_fin2(const float* __restrict__ p2, const float* __restrict__ g2,
                       const float* __restrict__ be2, const float* __restrict__ W3,
                       const float* __restrict__ b3, float* __restrict__ w3f,
                       float* __restrict__ b3f) {
  __shared__ float tp[64];
  const int t = threadIdx.x;
  if (t < 64) {
    float s = 0.f, q = 0.f;
    const float4* rs = (const float4*)(p2 + t * 512);
    const float4* rq = (const float4*)(p2 + 64 * 512 + t * 512);
#pragma unroll 4
    for (int i = 0; i < 128; ++i) {
      float4 a = rs[i]; s += a.x + a.y + a.z + a.w;
      float4 b = rq[i]; q += b.x + b.y + b.z + b.w;
    }
    const float inv = 1.0f / (float)NE;
    float mean = s * inv;
    float var = q * inv - mean * mean;
    float sc = g2[t] * rsqrtf(var + EPSBN);
    float tt = be2[t] - mean * sc;
    w3f[t] = sc * W3[t];
    tp[t] = tt * W3[t];
  }
  __syncthreads();
  if (t == 0) {
    float b = b3[0];
    for (int j = 0; j < 64; ++j) b += tp[j];
    b3f[0] = b;
  }
}

// out = tanh(x2 @ w3f + b3f); 4 lanes per edge
__global__ __launch_bounds__(256)
void k_out(const unsigned short* __restrict__ x2, const float* __restrict__ w3f,
           const float* __restrict__ b3f, float* __restrict__ out) {
  __shared__ float s_w[64];
  __shared__ float s_b;
  const int t = threadIdx.x;
  if (t < 64) s_w[t] = w3f[t];
  if (t == 0) s_b = b3f[0];
  __syncthreads();
  const int gid = blockIdx.x * 256 + t;
  const int e = gid >> 2, p = gid & 3;
  if (e < NE) {
    const uint4* r = (const uint4*)(x2 + (size_t)e * H2 + p * 16);
    float s = 0.f;
#pragma unroll
    for (int i = 0; i < 2; ++i) {
      const uint4 u = r[i];
      const int jb = p * 16 + i * 8;
      s += h2f(u.x) * s_w[jb + 0] + h2f(u.x >> 16) * s_w[jb + 1];
      s += h2f(u.y) * s_w[jb + 2] + h2f(u.y >> 16) * s_w[jb + 3];
      s += h2f(u.z) * s_w[jb + 4] + h2f(u.z >> 16) * s_w[jb + 5];
      s += h2f(u.w) * s_w[jb + 6] + h2f(u.w >> 16) * s_w[jb + 7];
    }
    s += __shfl_xor(s, 1);
    s += __shfl_xor(s, 2);
    if (p == 0) out[e] = tanhf(s + s_b);
  }
}

extern "C" void kernel_launch(void* const* d_in, const int* in_sizes, int n_in,
                              void* d_out, int out_size, void* d_ws, size_t ws_size,
                              hipStream_t stream) {
  const float* emb  = (const float*)d_in[0];
  const float* grad = (const float*)d_in[1];
  const float* step = (const float*)d_in[2];
  const float* W1   = (const float*)d_in[3];
  const float* b1   = (const float*)d_in[4];
  const float* g1   = (const float*)d_in[5];
  const float* be1  = (const float*)d_in[6];
  const float* W2   = (const float*)d_in[7];
  const float* b2   = (const float*)d_in[8];
  const float* g2   = (const float*)d_in[9];
  const float* be2  = (const float*)d_in[10];
  const float* W3   = (const float*)d_in[11];
  const float* b3   = (const float*)d_in[12];
  const void*  eidx = (const void*)d_in[13];
  float* out = (float*)d_out;

  char* ws = (char*)d_ws;
  // region A (64MB): embh (25.6MB) + bfrag + c0 + p1 during layer1/fin1;
  // x2 overwrites the whole region in layer2.
  _Float16* embh  = (_Float16*)(ws + 0);
  _Float16* x2    = (_Float16*)(ws + 0);
  _Float16* bfrag = (_Float16*)(ws + 25600000LL);  // 196,608 B
  float*    c0    = (float*)(ws + 25796608LL);     // 512 B
  float*    p1    = (float*)(ws + 26000000LL);     // 524,288 B (dead before layer2)
  _Float16* x1    = (_Float16*)(ws + 64000000LL);  // 128,000,000 B
  float* p2  = (float*)(ws + 192000000LL);         // 262,144 B
  float* w2f = (float*)(ws + 192524288LL);         // 32,768 B
  float* b2f = (float*)(ws + 192557056LL);         // 256 B
  float* w3f = (float*)(ws + 192557312LL);         // 256 B
  float* b3f = (float*)(ws + 192557568LL);         // 16 B

  k_preall<<<6299, 256, 0, stream>>>(emb, embh, W1, bfrag, b1, step, c0);
  k_layer1<<<GRID1,256, 0, stream>>>(embh, eidx, grad, W1, c0, bfrag, x1, p1);
  k_fin1  <<<1,    256, 0, stream>>>(p1, g1, be1, W2, b2, w2f, b2f);
  k_layer2<<<GRID2,256, 0, stream>>>(x1, w2f, b2f, x2, p2);
  k_fin2  <<<1,    128, 0, stream>>>(p2, g2, be2, W3, b3, w3f, b3f);
  k_out   <<<7813, 256, 0, stream>>>((const unsigned short*)x2, w3f, b3f, out);
}